// Round 1
// 650.522 us; speedup vs baseline: 1.0332x; 1.0332x over previous
//
#include <hip/hip_runtime.h>

#define MDIM 8192
#define NDIM 4096
#define KDIM 4096

typedef unsigned short u16;
typedef __attribute__((ext_vector_type(8))) short short8;
typedef __attribute__((ext_vector_type(4))) float f32x4;

// ---------- helpers ----------
__device__ __forceinline__ u16 f2b(float f) {  // fp32 -> bf16 RNE
  unsigned u = __float_as_uint(f);
  u += 0x7FFFu + ((u >> 16) & 1u);
  return (u16)(u >> 16);
}
__device__ __forceinline__ unsigned pk2(float a, float b) {
  return (unsigned)f2b(a) | ((unsigned)f2b(b) << 16);
}

// async global->LDS, 16B per lane, LDS dst = wave-uniform base + lane*16
__device__ __forceinline__ void async16(const u16* g, u16* l) {
  __builtin_amdgcn_global_load_lds(
      (const __attribute__((address_space(1))) unsigned*)g,
      (__attribute__((address_space(3))) unsigned*)l, 16, 0, 0);
}

// ---------- fused prep: W sample + KL partials (blocks < 8192),
//            x fp32->bf16 (blocks >= 8192, 16 elems/thread) ----------
__global__ __launch_bounds__(256) void k_prep(const float4* __restrict__ wmu,
                                              const float4* __restrict__ wsg,
                                              const float4* __restrict__ wep,
                                              uint4* __restrict__ wb,
                                              const float4* __restrict__ x,
                                              uint4* __restrict__ xb,
                                              float* __restrict__ partials) {
  const int bx = blockIdx.x;
  if (bx < 8192) {
    // ---- W = mu + exp(sig)*eps -> bf16, KL partial ----
    const int i = bx * 256 + (int)threadIdx.x;
    float part = 0.f;
    uint4 o;
    {
      float4 m = wmu[2 * i], s = wsg[2 * i], e = wep[2 * i];
      float e0 = __expf(s.x), e1 = __expf(s.y), e2 = __expf(s.z), e3 = __expf(s.w);
      o.x = pk2(m.x + e0 * e.x, m.y + e1 * e.y);
      o.y = pk2(m.z + e2 * e.z, m.w + e3 * e.w);
      part += (1.f + 2.f * s.x - m.x * m.x - e0 * e0)
            + (1.f + 2.f * s.y - m.y * m.y - e1 * e1)
            + (1.f + 2.f * s.z - m.z * m.z - e2 * e2)
            + (1.f + 2.f * s.w - m.w * m.w - e3 * e3);
    }
    {
      float4 m = wmu[2 * i + 1], s = wsg[2 * i + 1], e = wep[2 * i + 1];
      float e0 = __expf(s.x), e1 = __expf(s.y), e2 = __expf(s.z), e3 = __expf(s.w);
      o.z = pk2(m.x + e0 * e.x, m.y + e1 * e.y);
      o.w = pk2(m.z + e2 * e.z, m.w + e3 * e.w);
      part += (1.f + 2.f * s.x - m.x * m.x - e0 * e0)
            + (1.f + 2.f * s.y - m.y * m.y - e1 * e1)
            + (1.f + 2.f * s.z - m.z * m.z - e2 * e2)
            + (1.f + 2.f * s.w - m.w * m.w - e3 * e3);
    }
    wb[i] = o;
    for (int off = 32; off; off >>= 1) part += __shfl_down(part, off, 64);
    __shared__ float red[4];
    const int lane = threadIdx.x & 63, wv = threadIdx.x >> 6;
    if (lane == 0) red[wv] = part;
    __syncthreads();
    if (threadIdx.x == 0)
      partials[bx] = red[0] + red[1] + red[2] + red[3];
  } else {
    // ---- x -> bf16, two strided chunks of 8 elems each ----
    const int i0 = (bx - 8192) * 256 + (int)threadIdx.x;
#pragma unroll
    for (int c = 0; c < 2; ++c) {
      const int i = i0 + c * (8192 * 256);
      float4 a = x[2 * i], b = x[2 * i + 1];
      uint4 o;
      o.x = pk2(a.x, a.y); o.y = pk2(a.z, a.w);
      o.z = pk2(b.x, b.y); o.w = pk2(b.z, b.w);
      xb[i] = o;
    }
  }
}

// ---------- bias sample + final KL (1024 threads, 1 block) ----------
__global__ __launch_bounds__(1024) void k_bias(const float* __restrict__ bmu,
                                               const float* __restrict__ bsg,
                                               const float* __restrict__ bep,
                                               float* __restrict__ bias,
                                               const float* __restrict__ partials,
                                               int nPart,
                                               float* __restrict__ klOut) {
  float part = 0.f;
  for (int i = threadIdx.x; i < NDIM; i += 1024) {
    float s = bsg[i], m = bmu[i];
    float es = __expf(s);
    bias[i] = m + es * bep[i];
    part += 1.f + 2.f * s - m * m - es * es;
  }
  for (int i = threadIdx.x; i < nPart; i += 1024) part += partials[i];
  for (int off = 32; off; off >>= 1) part += __shfl_down(part, off, 64);
  __shared__ float red[16];
  const int lane = threadIdx.x & 63, wv = threadIdx.x >> 6;
  if (lane == 0) red[wv] = part;
  __syncthreads();
  if (threadIdx.x == 0) {
    float s = 0.f;
#pragma unroll
    for (int w = 0; w < 16; ++w) s += red[w];
    *klOut = -0.5f * s;
  }
}

// ---------- GEMM: C[m][n] = sum_k A[m][k]*B[n][k] + bias[n] ----------
// 256x256 tile, BK=64, 512 threads = 8 waves (2M x 4N), 8-phase counted-vmcnt
// schedule (T3+T4) + s_setprio around MFMA clusters (T5).
//
// LDS halves are K-SPLIT: each half = [256 rows][32 kcols] bf16 (64 B rows).
// Every mfma-fragment ds_read_b128 then addresses byte (row0+fr)*64 + fg*16 =
// 64 CONTIGUOUS 16B slots per wave -> bank-conflict-free with NO swizzle, and
// global_load_lds staging stays linear (dest = wave base + lane*16): both
// sides of rule #21 satisfied trivially.
//
// Stage schedule (per K-tile t, buf c=t&1, phases p1..p4):
//   p1: stage A1(t+1)->buf c^1    p2: stage B1(t+1)->buf c^1
//   p3: stage A0(t+2)->buf c      p4: stage B0(t+2)->buf c, vmcnt(4)
// A0/B0 of buf c are last read at p2, so p3/p4's overwrite is barrier-
// separated; every half is staged 5-6 phases (~1000 cy) before first use.
// vmcnt(4) at p4/p8 leaves exactly the 2 newest half-tiles in flight -- the
// queue never drains to 0 in the main loop.
__global__ __launch_bounds__(512, 2) void k_gemm(const u16* __restrict__ A,
                                                 const u16* __restrict__ B,
                                                 const float* __restrict__ bias,
                                                 float* __restrict__ C) {
  // [buf][khalf][row*32 + kcol] ; 2*2*16KB per operand = 128 KiB total
  __shared__ u16 sA[2][2][8192];
  __shared__ u16 sB[2][2][8192];

  const int tid = threadIdx.x;
  const int wave = tid >> 6, lane = tid & 63;
  const int fr = lane & 15;          // row (A) / col (B) within 16x16 frag
  const int fg = lane >> 4;          // k-group: holds k = fg*8 .. fg*8+7
  const int wm128 = (wave >> 2) * 128;   // wave's 128-row A strip
  const int wn64  = (wave & 3) * 64;     // wave's 64-col B strip
  const int w512  = wave << 9;           // per-wave stage base, u16 elems

  // bm-fastest block mapping: 32 consecutive blocks share a B panel (L2),
  // A (67MB) + B (33MB) are L3-resident so no XCD swizzle (costs ~2% L3-fit).
  const int bm = (blockIdx.x & 31) * 256;
  const int bn = (blockIdx.x >> 5) * 256;

  // per-thread global stage pointers: row = tid>>2 (+128 round 1), col=(tid&3)*8
  const u16* gA = A + (size_t)(bm + (tid >> 2)) * KDIM + (tid & 3) * 8;
  const u16* gB = B + (size_t)(bn + (tid >> 2)) * KDIM + (tid & 3) * 8;

#define STG(g, larr, ks)                                                     \
  do {                                                                       \
    async16((g) + (ks), &(larr)[0] + w512);                                  \
    async16((g) + (size_t)128 * KDIM + (ks), &(larr)[0] + 4096 + w512);      \
  } while (0)

  f32x4 acc[8][4] = {};

  // prologue: tile0 fully + tile1's k-half0; leaves A0(1),B0(1) in flight (=4)
  STG(gA, sA[0][0], 0);
  STG(gB, sB[0][0], 0);
  STG(gA, sA[0][1], 32);
  STG(gB, sB[0][1], 32);
  STG(gA, sA[1][0], 64);
  STG(gB, sB[1][0], 64);
  asm volatile("s_waitcnt vmcnt(4)" ::: "memory");
  __builtin_amdgcn_s_barrier();

  // one phase: 8 ds_read_b128 || 2 global_load_lds -> barrier -> lgkmcnt(0)
  //            -> setprio(1) 16 MFMA setprio(0) -> [vmcnt(4)] -> barrier
#define PHASE(BUF, H, QM, STAGE_STMT, TILE_END)                               \
  {                                                                           \
    short8 af[4], bf[4];                                                      \
    _Pragma("unroll") for (int x = 0; x < 4; ++x) {                           \
      af[x] = *(const short8*)&sA[BUF][H][(wm128 + (QM)*64 + x*16 + fr)*32 + fg*8]; \
      bf[x] = *(const short8*)&sB[BUF][H][(wn64 + x*16 + fr)*32 + fg*8];      \
    }                                                                         \
    STAGE_STMT;                                                               \
    __builtin_amdgcn_s_barrier();                                             \
    asm volatile("s_waitcnt lgkmcnt(0)" ::: "memory");                        \
    __builtin_amdgcn_sched_barrier(0);                                        \
    __builtin_amdgcn_s_setprio(1);                                            \
    _Pragma("unroll") for (int x = 0; x < 4; ++x)                             \
      _Pragma("unroll") for (int y = 0; y < 4; ++y)                           \
        acc[(QM)*4 + x][y] = __builtin_amdgcn_mfma_f32_16x16x32_bf16(         \
            af[x], bf[y], acc[(QM)*4 + x][y], 0, 0, 0);                       \
    __builtin_amdgcn_s_setprio(0);                                            \
    if (TILE_END) asm volatile("s_waitcnt vmcnt(4)" ::: "memory");            \
    __builtin_amdgcn_s_barrier();                                             \
  }

  for (int i = 0; i < 32; ++i) {
    const int t = 2 * i;
    int s1 = t + 1; if (s1 > 63) s1 = 63;  // clamped tail stages are
    int s2 = t + 2; if (s2 > 63) s2 = 63;  // harmless redundant loads into
    int s3 = t + 3; if (s3 > 63) s3 = 63;  // slots that are never read again
    const int k1  = s1 * 64 + 32;  // A1/B1(t+1)
    const int k2a = s2 * 64;       // A0/B0(t+2)
    const int k2b = s2 * 64 + 32;  // A1/B1(t+2)
    const int k3  = s3 * 64;       // A0/B0(t+3)

    // tile t (buf0): k-half0 (qm=0,1) then k-half1 (qm=0,1)
    PHASE(0, 0, 0, STG(gA, sA[1][1], k1),  false)
    PHASE(0, 0, 1, STG(gB, sB[1][1], k1),  false)
    PHASE(0, 1, 0, STG(gA, sA[0][0], k2a), false)
    PHASE(0, 1, 1, STG(gB, sB[0][0], k2a), true)
    // tile t+1 (buf1)
    PHASE(1, 0, 0, STG(gA, sA[0][1], k2b), false)
    PHASE(1, 0, 1, STG(gB, sB[0][1], k2b), false)
    PHASE(1, 1, 0, STG(gA, sA[1][0], k3),  false)
    PHASE(1, 1, 1, STG(gB, sB[1][0], k3),  true)
  }
#undef PHASE
#undef STG

  // epilogue: C/D layout col=lane&15, row=(lane>>4)*4+reg  [m89-verified]
#pragma unroll
  for (int y = 0; y < 4; ++y) {
    const int gn = bn + wn64 + y * 16 + fr;
    const float bv = bias[gn];
#pragma unroll
    for (int x = 0; x < 8; ++x) {
      const int gm0 = bm + wm128 + x * 16 + fg * 4;
      float* Cp = C + (size_t)gm0 * NDIM + gn;
#pragma unroll
      for (int r = 0; r < 4; ++r)
        Cp[(size_t)r * NDIM] = acc[x][y][r] + bv;
    }
  }
}

// ---------- launch ----------
extern "C" void kernel_launch(void* const* d_in, const int* in_sizes, int n_in,
                              void* d_out, int out_size, void* d_ws, size_t ws_size,
                              hipStream_t stream) {
  const float* x    = (const float*)d_in[0];
  const float* wmu  = (const float*)d_in[1];
  const float* wsig = (const float*)d_in[2];
  const float* bmu  = (const float*)d_in[3];
  const float* bsig = (const float*)d_in[4];
  const float* ew   = (const float*)d_in[5];
  const float* eb   = (const float*)d_in[6];
  float* out = (float*)d_out;

  char* ws = (char*)d_ws;
  u16*   xb       = (u16*)ws;                          // 67108864 B
  u16*   wb       = (u16*)(ws + 67108864);             // 33554432 B
  float* bias     = (float*)(ws + 100663296);          // 16384 B
  float* partials = (float*)(ws + 100679680);          // 8192*4 B

  // fused W-sample/KL-partials + x-cast (one streaming dispatch)
  k_prep<<<16384, 256, 0, stream>>>((const float4*)wmu, (const float4*)wsig,
                                    (const float4*)ew, (uint4*)wb,
                                    (const float4*)x, (uint4*)xb, partials);
  // bias sample + KL finalize
  k_bias<<<1, 1024, 0, stream>>>(bmu, bsig, eb, bias, partials, 8192,
                                 out + (size_t)MDIM * NDIM);
  // GEMM: 32 m-tiles x 16 n-tiles, 512 threads
  k_gemm<<<512, 512, 0, stream>>>(xb, wb, bias, out);
}

// Round 2
// 617.214 us; speedup vs baseline: 1.0890x; 1.0540x over previous
//
#include <hip/hip_runtime.h>

#define MDIM 8192
#define NDIM 4096
#define KDIM 4096

typedef unsigned short u16;
typedef __attribute__((ext_vector_type(8))) short short8;
typedef __attribute__((ext_vector_type(4))) float f32x4;

// ---------- helpers ----------
__device__ __forceinline__ u16 f2b(float f) {  // fp32 -> bf16 RNE
  unsigned u = __float_as_uint(f);
  u += 0x7FFFu + ((u >> 16) & 1u);
  return (u16)(u >> 16);
}
__device__ __forceinline__ unsigned pk2(float a, float b) {
  return (unsigned)f2b(a) | ((unsigned)f2b(b) << 16);
}

// async global->LDS, 16B per lane, LDS dst = wave-uniform base + lane*16
__device__ __forceinline__ void async16(const u16* g, u16* l) {
  __builtin_amdgcn_global_load_lds(
      (const __attribute__((address_space(1))) unsigned*)g,
      (__attribute__((address_space(3))) unsigned*)l, 16, 0, 0);
}

// ---------- fused prep: W sample + KL partials (blocks < 8192),
//            x fp32->bf16 (blocks >= 8192, 16 elems/thread) ----------
__global__ __launch_bounds__(256) void k_prep(const float4* __restrict__ wmu,
                                              const float4* __restrict__ wsg,
                                              const float4* __restrict__ wep,
                                              uint4* __restrict__ wb,
                                              const float4* __restrict__ x,
                                              uint4* __restrict__ xb,
                                              float* __restrict__ partials) {
  const int bx = blockIdx.x;
  if (bx < 8192) {
    // ---- W = mu + exp(sig)*eps -> bf16, KL partial ----
    const int i = bx * 256 + (int)threadIdx.x;
    float part = 0.f;
    uint4 o;
    {
      float4 m = wmu[2 * i], s = wsg[2 * i], e = wep[2 * i];
      float e0 = __expf(s.x), e1 = __expf(s.y), e2 = __expf(s.z), e3 = __expf(s.w);
      o.x = pk2(m.x + e0 * e.x, m.y + e1 * e.y);
      o.y = pk2(m.z + e2 * e.z, m.w + e3 * e.w);
      part += (1.f + 2.f * s.x - m.x * m.x - e0 * e0)
            + (1.f + 2.f * s.y - m.y * m.y - e1 * e1)
            + (1.f + 2.f * s.z - m.z * m.z - e2 * e2)
            + (1.f + 2.f * s.w - m.w * m.w - e3 * e3);
    }
    {
      float4 m = wmu[2 * i + 1], s = wsg[2 * i + 1], e = wep[2 * i + 1];
      float e0 = __expf(s.x), e1 = __expf(s.y), e2 = __expf(s.z), e3 = __expf(s.w);
      o.z = pk2(m.x + e0 * e.x, m.y + e1 * e.y);
      o.w = pk2(m.z + e2 * e.z, m.w + e3 * e.w);
      part += (1.f + 2.f * s.x - m.x * m.x - e0 * e0)
            + (1.f + 2.f * s.y - m.y * m.y - e1 * e1)
            + (1.f + 2.f * s.z - m.z * m.z - e2 * e2)
            + (1.f + 2.f * s.w - m.w * m.w - e3 * e3);
    }
    wb[i] = o;
    for (int off = 32; off; off >>= 1) part += __shfl_down(part, off, 64);
    __shared__ float red[4];
    const int lane = threadIdx.x & 63, wv = threadIdx.x >> 6;
    if (lane == 0) red[wv] = part;
    __syncthreads();
    if (threadIdx.x == 0)
      partials[bx] = red[0] + red[1] + red[2] + red[3];
  } else {
    // ---- x -> bf16, two strided chunks of 8 elems each ----
    const int i0 = (bx - 8192) * 256 + (int)threadIdx.x;
#pragma unroll
    for (int c = 0; c < 2; ++c) {
      const int i = i0 + c * (8192 * 256);
      float4 a = x[2 * i], b = x[2 * i + 1];
      uint4 o;
      o.x = pk2(a.x, a.y); o.y = pk2(a.z, a.w);
      o.z = pk2(b.x, b.y); o.w = pk2(b.z, b.w);
      xb[i] = o;
    }
  }
}

// ---------- bias sample + final KL (1024 threads, 1 block) ----------
__global__ __launch_bounds__(1024) void k_bias(const float* __restrict__ bmu,
                                               const float* __restrict__ bsg,
                                               const float* __restrict__ bep,
                                               float* __restrict__ bias,
                                               const float* __restrict__ partials,
                                               int nPart,
                                               float* __restrict__ klOut) {
  float part = 0.f;
  for (int i = threadIdx.x; i < NDIM; i += 1024) {
    float s = bsg[i], m = bmu[i];
    float es = __expf(s);
    bias[i] = m + es * bep[i];
    part += 1.f + 2.f * s - m * m - es * es;
  }
  for (int i = threadIdx.x; i < nPart; i += 1024) part += partials[i];
  for (int off = 32; off; off >>= 1) part += __shfl_down(part, off, 64);
  __shared__ float red[16];
  const int lane = threadIdx.x & 63, wv = threadIdx.x >> 6;
  if (lane == 0) red[wv] = part;
  __syncthreads();
  if (threadIdx.x == 0) {
    float s = 0.f;
#pragma unroll
    for (int w = 0; w < 16; ++w) s += red[w];
    *klOut = -0.5f * s;
  }
}

// ---------- GEMM: C[m][n] = sum_k A[m][k]*B[n][k] + bias[n] ----------
// 256x256 tile, BK=64, 8 waves (2M x 4N), 8-phase counted-vmcnt schedule
// (T3+T4) + setprio (T5) + LDS k-slot XOR swizzle (T2, adapted to K-split
// layout) + B-fragment register caching (24 ds_read_b128 / K-tile / wave).
//
// LDS halves are K-SPLIT: each half = [256 rows][32 kcols] bf16, 64 B rows
// = 4 16B k-slots. SWIZZLE: logical k-slot g of row r lives at phys slot
// g ^ ((r>>1)&3). A lane-order beat of 8 lanes (fg fixed, fr=0..7) then
// hits bank-starts {0,16,4,20,8,24,12,28} -> all 32 banks exactly once.
//  - stage side: global_load_lds keeps LINEAR dest (slot = tid); the per-
//    lane GLOBAL column is pre-permuted: gq = (tid&3) ^ ((tid>>3)&3)
//    (rule #21: linear dest + inverse-swizzled source + swizzled read).
//  - read side: fragment row-bases are multiples of 16, so
//    (row>>1)&3 == (fr>>1)&3 -> per-lane constant fgp = fg ^ ((fr>>1)&3);
//    zero extra per-read cost.
//
// Stage schedule + vmcnt placement identical to the verified round-1 kernel:
// per K-tile t (buf c), phases p1..p4 stage A1/B1(t+1), A0/B0(t+2); vmcnt(4)
// at p4/p8 only (never 0 in main loop); every half guaranteed landed by a
// counted wait >=1 full tile before its first read.
__global__ __launch_bounds__(512, 2) void k_gemm(const u16* __restrict__ A,
                                                 const u16* __restrict__ B,
                                                 const float* __restrict__ bias,
                                                 float* __restrict__ C) {
  // [buf][khalf][row*32 + kcol] ; 2*2*16KB per operand = 128 KiB total
  __shared__ u16 sA[2][2][8192];
  __shared__ u16 sB[2][2][8192];

  const int tid = threadIdx.x;
  const int wave = tid >> 6, lane = tid & 63;
  const int fr = lane & 15;          // row (A) / col (B) within 16x16 frag
  const int fg = lane >> 4;          // k-group: holds k = fg*8 .. fg*8+7
  const int fgp = fg ^ ((fr >> 1) & 3);  // swizzled phys k-slot (see header)
  const int wm128 = (wave >> 2) * 128;   // wave's 128-row A strip
  const int wn64  = (wave & 3) * 64;     // wave's 64-col B strip
  const int w512  = wave << 9;           // per-wave stage base, u16 elems

  // bm-fastest block mapping: 32 consecutive blocks share a B panel (L2),
  // A (67MB) + B (33MB) are L3-resident so no XCD swizzle (costs ~2% L3-fit).
  const int bm = (blockIdx.x & 31) * 256;
  const int bn = (blockIdx.x >> 5) * 256;

  // per-thread global stage pointers: row = tid>>2 (+128 second load),
  // col = swizzle-permuted k-slot gq*8  (gq = (tid&3) ^ ((row>>1)&3))
  const int gq = (tid & 3) ^ ((tid >> 3) & 3);
  const u16* gA = A + (size_t)(bm + (tid >> 2)) * KDIM + gq * 8;
  const u16* gB = B + (size_t)(bn + (tid >> 2)) * KDIM + gq * 8;

#define STG(g, larr, ks)                                                     \
  do {                                                                       \
    async16((g) + (ks), &(larr)[0] + w512);                                  \
    async16((g) + (size_t)128 * KDIM + (ks), &(larr)[0] + 4096 + w512);      \
  } while (0)

  f32x4 acc[8][4] = {};
  short8 af[4], bf[4];

  // prologue: tile0 fully + tile1's k-half0; leaves A0(1),B0(1) in flight (=4)
  STG(gA, sA[0][0], 0);
  STG(gB, sB[0][0], 0);
  STG(gA, sA[0][1], 32);
  STG(gB, sB[0][1], 32);
  STG(gA, sA[1][0], 64);
  STG(gB, sB[1][0], 64);
  asm volatile("s_waitcnt vmcnt(4)" ::: "memory");
  __builtin_amdgcn_s_barrier();

  // one phase: {4 or 8} ds_read_b128 || 2 global_load_lds -> barrier ->
  //            lgkmcnt(0) -> setprio(1) 16 MFMA setprio(0) -> [vmcnt(4)]
  //            -> barrier.  RDB=1 phases load bf[]; RDB=0 reuse registers.
#define PHASE(BUF, H, QM, RDB, STAGE_STMT, TILE_END)                          \
  {                                                                           \
    _Pragma("unroll") for (int x = 0; x < 4; ++x) {                           \
      af[x] = *(const short8*)&sA[BUF][H][(wm128 + (QM)*64 + x*16 + fr)*32 + fgp*8]; \
      if (RDB)                                                                \
        bf[x] = *(const short8*)&sB[BUF][H][(wn64 + x*16 + fr)*32 + fgp*8];   \
    }                                                                         \
    STAGE_STMT;                                                               \
    __builtin_amdgcn_s_barrier();                                             \
    asm volatile("s_waitcnt lgkmcnt(0)" ::: "memory");                        \
    __builtin_amdgcn_sched_barrier(0);                                        \
    __builtin_amdgcn_s_setprio(1);                                            \
    _Pragma("unroll") for (int x = 0; x < 4; ++x)                             \
      _Pragma("unroll") for (int y = 0; y < 4; ++y)                           \
        acc[(QM)*4 + x][y] = __builtin_amdgcn_mfma_f32_16x16x32_bf16(         \
            af[x], bf[y], acc[(QM)*4 + x][y], 0, 0, 0);                       \
    __builtin_amdgcn_s_setprio(0);                                            \
    if (TILE_END) asm volatile("s_waitcnt vmcnt(4)" ::: "memory");            \
    __builtin_amdgcn_s_barrier();                                             \
  }

  for (int i = 0; i < 32; ++i) {
    const int t = 2 * i;
    int s1 = t + 1; if (s1 > 63) s1 = 63;  // clamped tail stages are
    int s2 = t + 2; if (s2 > 63) s2 = 63;  // harmless redundant loads into
    int s3 = t + 3; if (s3 > 63) s3 = 63;  // slots that are never read again
    const int k1  = s1 * 64 + 32;  // A1/B1(t+1)
    const int k2a = s2 * 64;       // A0/B0(t+2)
    const int k2b = s2 * 64 + 32;  // A1/B1(t+2)
    const int k3  = s3 * 64;       // A0/B0(t+3)

    // tile t (buf0): k-half0 (qm=0,1) then k-half1 (qm=0,1)
    PHASE(0, 0, 0, 1, STG(gA, sA[1][1], k1),  false)
    PHASE(0, 0, 1, 0, STG(gB, sB[1][1], k1),  false)
    PHASE(0, 1, 0, 1, STG(gA, sA[0][0], k2a), false)
    PHASE(0, 1, 1, 0, STG(gB, sB[0][0], k2a), true)
    // tile t+1 (buf1)
    PHASE(1, 0, 0, 1, STG(gA, sA[0][1], k2b), false)
    PHASE(1, 0, 1, 0, STG(gB, sB[0][1], k2b), false)
    PHASE(1, 1, 0, 1, STG(gA, sA[1][0], k3),  false)
    PHASE(1, 1, 1, 0, STG(gB, sB[1][0], k3),  true)
  }
#undef PHASE
#undef STG

  // epilogue: C/D layout col=lane&15, row=(lane>>4)*4+reg  [m89-verified]
#pragma unroll
  for (int y = 0; y < 4; ++y) {
    const int gn = bn + wn64 + y * 16 + fr;
    const float bv = bias[gn];
#pragma unroll
    for (int x = 0; x < 8; ++x) {
      const int gm0 = bm + wm128 + x * 16 + fg * 4;
      float* Cp = C + (size_t)gm0 * NDIM + gn;
#pragma unroll
      for (int r = 0; r < 4; ++r)
        Cp[(size_t)r * NDIM] = acc[x][y][r] + bv;
    }
  }
}

// ---------- launch ----------
extern "C" void kernel_launch(void* const* d_in, const int* in_sizes, int n_in,
                              void* d_out, int out_size, void* d_ws, size_t ws_size,
                              hipStream_t stream) {
  const float* x    = (const float*)d_in[0];
  const float* wmu  = (const float*)d_in[1];
  const float* wsig = (const float*)d_in[2];
  const float* bmu  = (const float*)d_in[3];
  const float* bsig = (const float*)d_in[4];
  const float* ew   = (const float*)d_in[5];
  const float* eb   = (const float*)d_in[6];
  float* out = (float*)d_out;

  char* ws = (char*)d_ws;
  u16*   xb       = (u16*)ws;                          // 67108864 B
  u16*   wb       = (u16*)(ws + 67108864);             // 33554432 B
  float* bias     = (float*)(ws + 100663296);          // 16384 B
  float* partials = (float*)(ws + 100679680);          // 8192*4 B

  // fused W-sample/KL-partials + x-cast (one streaming dispatch)
  k_prep<<<16384, 256, 0, stream>>>((const float4*)wmu, (const float4*)wsig,
                                    (const float4*)ew, (uint4*)wb,
                                    (const float4*)x, (uint4*)xb, partials);
  // bias sample + KL finalize
  k_bias<<<1, 1024, 0, stream>>>(bmu, bsig, eb, bias, partials, 8192,
                                 out + (size_t)MDIM * NDIM);
  // GEMM: 32 m-tiles x 16 n-tiles, 512 threads
  k_gemm<<<512, 512, 0, stream>>>(xb, wb, bias, out);
}